// Round 1
// baseline (582.183 us; speedup 1.0000x reference)
//
#include <hip/hip_runtime.h>
#include <hip/hip_bf16.h>
#include <cstdint>

// Problem dims (fixed by the reference)
#define M_DIM 8192   // batch B
#define K_DIM 2048   // N_IN
#define N_DIM 2048   // N_OUT

typedef short short8 __attribute__((ext_vector_type(8)));   // 8 bf16 raw bits
typedef float f32x4  __attribute__((ext_vector_type(4)));

// ---------------------------------------------------------------------------
// f32 -> bf16 (RNE) conversion of xt + 4 weight matrices into workspace.
// Memory-bound: vectorized 2x float4 read, 16B short8 write per iter.
// ---------------------------------------------------------------------------
__global__ void convert_bf16_kernel(const float* __restrict__ xt,
                                    const float* __restrict__ w0,
                                    const float* __restrict__ w1,
                                    const float* __restrict__ w2,
                                    const float* __restrict__ w3,
                                    short* __restrict__ out) {
    const long MK = (long)M_DIM * K_DIM;        // 16777216
    const long NK = (long)N_DIM * K_DIM;        // 4194304
    const long total8 = (MK + 4 * NK) >> 3;     // groups of 8 elems
    for (long i8 = (long)blockIdx.x * blockDim.x + threadIdx.x; i8 < total8;
         i8 += (long)gridDim.x * blockDim.x) {
        long e = i8 << 3;
        const float* src;
        if (e < MK) {
            src = xt + e;
        } else {
            long r = e - MK;
            int g = (int)(r / NK);
            long o = r - (long)g * NK;
            src = (g == 0 ? w0 : g == 1 ? w1 : g == 2 ? w2 : w3) + o;
        }
        float4 v0 = *(const float4*)(src);
        float4 v1 = *(const float4*)(src + 4);
        float vals[8] = {v0.x, v0.y, v0.z, v0.w, v1.x, v1.y, v1.z, v1.w};
        short8 s;
#pragma unroll
        for (int j = 0; j < 8; ++j) {
            uint32_t u = __float_as_uint(vals[j]);
            u = (u + 0x7FFFu + ((u >> 16) & 1u)) >> 16;   // round-nearest-even
            s[j] = (short)u;
        }
        *(short8*)(out + e) = s;
    }
}

// ---------------------------------------------------------------------------
// Stage a 128x64 bf16 tile (row-major, leading dim = ld elems) into LDS via
// global_load_lds width=16. LDS dest = wave-uniform base + lane*16 (linear).
// ---------------------------------------------------------------------------
__device__ __forceinline__ void stage_tile(const short* __restrict__ src, int ld,
                                           short* lds, int tid) {
#pragma unroll
    for (int j = 0; j < 4; ++j) {
        int slot = j * 256 + tid;          // 1024 slots of 16B = 128*64*2B
        int row  = slot >> 3;              // 8 slots per 64-elem row
        int c8   = (slot & 7) << 3;
        const short* g = src + (long)row * ld + c8;
        __builtin_amdgcn_global_load_lds(
            (const __attribute__((address_space(1))) void*)g,
            (__attribute__((address_space(3))) void*)(lds + slot * 8),
            16, 0, 0);
    }
}

// ---------------------------------------------------------------------------
// Dual-GEMM + fused SRU gate epilogue.
// MODE 0: acc0 = xt@W_x^T (no bias), acc1 = xt@W_f^T; out = ct
//         ct = sig(acc1+b1)*extra + (1-sig)*acc0        (extra = ct_forward)
// MODE 1: acc0 = xt@W_r^T, acc1 = xt@W_c^T; out = ht
//         ht = sig(acc0+b0)*tanh(extra) + (1-sig)*(acc1+b1)   (extra = ct)
// 128x128 tile, BK=64, 4 waves (2x2), each wave 64x64 per gate.
// ---------------------------------------------------------------------------
template <int MODE>
__launch_bounds__(256, 2)
__global__ void sru_gemm_kernel(const short* __restrict__ Ab,   // [M][K] bf16
                                const short* __restrict__ W0b,  // [N][K] bf16
                                const short* __restrict__ W1b,  // [N][K] bf16
                                const float* __restrict__ bias0,
                                const float* __restrict__ bias1,
                                const float* __restrict__ extra, // [M][N]
                                float* __restrict__ out) {       // [M][N]
    __shared__ short sA [128 * 64];
    __shared__ short sB0[128 * 64];
    __shared__ short sB1[128 * 64];

    const int tid  = threadIdx.x;
    const int lane = tid & 63;
    const int wid  = tid >> 6;
    const int wr   = wid >> 1;      // wave row (0..1)
    const int wc   = wid & 1;       // wave col (0..1)

    const int bn = blockIdx.x & 15;        // N/128 = 16
    const int bm = blockIdx.x >> 4;        // M/128 = 64
    const int rowBase = bm * 128;
    const int colBase = bn * 128;

    f32x4 acc0[4][4];
    f32x4 acc1[4][4];
#pragma unroll
    for (int m = 0; m < 4; ++m)
#pragma unroll
        for (int n = 0; n < 4; ++n) {
            acc0[m][n] = (f32x4){0.f, 0.f, 0.f, 0.f};
            acc1[m][n] = (f32x4){0.f, 0.f, 0.f, 0.f};
        }

    const short* Ablk  = Ab  + (long)rowBase * K_DIM;
    const short* B0blk = W0b + (long)colBase * K_DIM;
    const short* B1blk = W1b + (long)colBase * K_DIM;

    const int lrow = lane & 15;
    const int lk   = (lane >> 4) << 3;   // 0,8,16,24

    for (int kt = 0; kt < K_DIM; kt += 64) {
        stage_tile(Ablk  + kt, K_DIM, sA,  tid);
        stage_tile(B0blk + kt, K_DIM, sB0, tid);
        stage_tile(B1blk + kt, K_DIM, sB1, tid);
        __syncthreads();   // drains vmcnt before barrier (compiler-emitted)

#pragma unroll
        for (int kk = 0; kk < 2; ++kk) {
            const int off = kk * 32 + lk;
            short8 a[4], b0[4], b1[4];
#pragma unroll
            for (int m = 0; m < 4; ++m)
                a[m] = *(const short8*)&sA[(wr * 64 + m * 16 + lrow) * 64 + off];
#pragma unroll
            for (int n = 0; n < 4; ++n) {
                b0[n] = *(const short8*)&sB0[(wc * 64 + n * 16 + lrow) * 64 + off];
                b1[n] = *(const short8*)&sB1[(wc * 64 + n * 16 + lrow) * 64 + off];
            }
#pragma unroll
            for (int m = 0; m < 4; ++m)
#pragma unroll
                for (int n = 0; n < 4; ++n) {
                    acc0[m][n] = __builtin_amdgcn_mfma_f32_16x16x32_bf16(
                        a[m], b0[n], acc0[m][n], 0, 0, 0);
                    acc1[m][n] = __builtin_amdgcn_mfma_f32_16x16x32_bf16(
                        a[m], b1[n], acc1[m][n], 0, 0, 0);
                }
        }
        __syncthreads();
    }

    // Epilogue. D mapping (m89-verified): col = lane&15, row = (lane>>4)*4 + reg.
    const int lr4 = (lane >> 4) << 2;
#pragma unroll
    for (int n = 0; n < 4; ++n) {
        const int col = colBase + wc * 64 + n * 16 + lrow;
        const float b0v = (MODE == 1) ? bias0[col] : 0.f;
        const float b1v = bias1[col];
#pragma unroll
        for (int m = 0; m < 4; ++m) {
#pragma unroll
            for (int r = 0; r < 4; ++r) {
                const int row = rowBase + wr * 64 + m * 16 + lr4 + r;
                const long idx = (long)row * N_DIM + col;
                const float v0 = acc0[m][n][r];
                const float v1 = acc1[m][n][r];
                if (MODE == 0) {
                    const float f = 1.f / (1.f + __expf(-(v1 + b1v)));
                    out[idx] = f * extra[idx] + (1.f - f) * v0;
                } else {
                    const float rt = 1.f / (1.f + __expf(-(v0 + b0v)));
                    const float xc = v1 + b1v;
                    out[idx] = rt * tanhf(extra[idx]) + (1.f - rt) * xc;
                }
            }
        }
    }
}

// ---------------------------------------------------------------------------
extern "C" void kernel_launch(void* const* d_in, const int* in_sizes, int n_in,
                              void* d_out, int out_size, void* d_ws, size_t ws_size,
                              hipStream_t stream) {
    const float* xt  = (const float*)d_in[0];
    const float* ctf = (const float*)d_in[1];
    const float* W_x = (const float*)d_in[2];
    const float* W_f = (const float*)d_in[3];
    const float* b_f = (const float*)d_in[4];
    const float* W_r = (const float*)d_in[5];
    const float* b_r = (const float*)d_in[6];
    const float* W_c = (const float*)d_in[7];
    const float* b_c = (const float*)d_in[8];

    float* ht = (float*)d_out;                                   // output 0
    float* ct = (float*)d_out + (long)M_DIM * N_DIM;             // output 1

    // Workspace: bf16 xt [M][K], then bf16 W_x, W_f, W_r, W_c [N][K] each.
    short* xtb = (short*)d_ws;
    short* Wxb = xtb + (long)M_DIM * K_DIM;
    short* Wfb = Wxb + (long)N_DIM * K_DIM;
    short* Wrb = Wfb + (long)N_DIM * K_DIM;
    short* Wcb = Wrb + (long)N_DIM * K_DIM;

    convert_bf16_kernel<<<2048, 256, 0, stream>>>(xt, W_x, W_f, W_r, W_c, xtb);

    dim3 grid((M_DIM / 128) * (N_DIM / 128));   // 64 * 16 = 1024 blocks
    // Kernel 1: x_t & f gates -> ct (written straight to its output slot)
    sru_gemm_kernel<0><<<grid, 256, 0, stream>>>(xtb, Wxb, Wfb, nullptr, b_f,
                                                 ctf, ct);
    // Kernel 2: r & c gates + ct -> ht
    sru_gemm_kernel<1><<<grid, 256, 0, stream>>>(xtb, Wrb, Wcb, b_r, b_c,
                                                 ct, ht);
}